// Round 1
// baseline (1430.892 us; speedup 1.0000x reference)
//
#include <hip/hip_runtime.h>

// MHA fused forward: x = (softmax(split(QWq^T+bq) @ split(KWk^T+bk)^T / 8, mask) @ split(VWv^T+bv)) merged @ Wo^T + bo
// B=4 N=1024 D=1024 H=16 DH=64.  Outputs: x [4,1024,1024] fp32 then weights [4,16,1024,1024] fp32.

#define SEQ   1024
#define D_DIM 1024
#define HEADS 16
#define DHEAD 64
#define BATCH 4

typedef __attribute__((ext_vector_type(8))) short bhalf8;
typedef __attribute__((ext_vector_type(4))) float floatx4;

static __device__ __forceinline__ unsigned short f2b(float f) {
    // fp32 -> bf16 round-to-nearest-even (inputs are finite randoms; NaN path not needed)
    unsigned int u = __float_as_uint(f);
    u += 0x7FFFu + ((u >> 16) & 1u);
    return (unsigned short)(u >> 16);
}

// ---------------------------------------------------------------------------
// Mask dtype probe: bool from jax may arrive as uint8, int32 or fp32. Scan 1MB
// of words: any word not in {0, 1, 0x3F800000} => byte-packed elements.
// (int32 bool: words are 0/1. fp32 bool: words are 0/0x3F800000. uint8 bool at
// 10% density over 256K words is certain to produce a mixed-byte word.)
// For 4-byte elements, int32 and fp32 both reduce to "word != 0".
// ---------------------------------------------------------------------------
__global__ __launch_bounds__(256) void detect_mask_kernel(const unsigned int* __restrict__ m,
                                                          int* __restrict__ flag) {
    __shared__ int found;
    if (threadIdx.x == 0) found = 0;
    __syncthreads();
    int loc = 0;
    for (int i = threadIdx.x; i < 262144; i += 256) {
        unsigned int w = m[i];
        if (w != 0u && w != 1u && w != 0x3F800000u) loc = 1;
    }
    if (loc) atomicOr(&found, 1);
    __syncthreads();
    if (threadIdx.x == 0) *flag = found;  // 1 = byte elements, 0 = 4-byte elements
}

// ---------------------------------------------------------------------------
// GEMM: Out[m, n] = sum_k A[m, k] * W[n, k] + bias[n]   (torch Linear, W row-major [out,in])
// M=4096, N=1024, K=1024. 128x128 tile, BK=64, 4 waves (2x2), 4x4 MFMA tiles/wave.
// AMODE 0: A fp32 (convert to bf16 during staging); AMODE 1: A bf16.
// OMODE 0: write bf16 scattered to [b,h,n,dh] (+bias); OMODE 1: write fp32 row-major (+bias).
// ---------------------------------------------------------------------------
template <int AMODE, int OMODE>
__global__ __launch_bounds__(256) void gemm_bt(const void* __restrict__ Aptr,
                                               const float* __restrict__ W,
                                               const float* __restrict__ bias,
                                               void* __restrict__ Out) {
    __shared__ unsigned short Al[128 * 72];  // +8 pad: row stride 144B -> 2-way bank alias (free)
    __shared__ unsigned short Bl[128 * 72];

    const int tid = threadIdx.x;
    const int lane = tid & 63, wid = tid >> 6;
    const int lr = lane & 15, lq = lane >> 4;
    const int wm = (wid & 1) * 64, wn = (wid >> 1) * 64;
    const int rowBase = blockIdx.y * 128;
    const int colBase = blockIdx.x * 128;

    floatx4 acc[4][4];
    for (int mi = 0; mi < 4; ++mi)
        for (int ni = 0; ni < 4; ++ni)
            for (int r = 0; r < 4; ++r) acc[mi][ni][r] = 0.f;

    for (int k0 = 0; k0 < D_DIM; k0 += 64) {
        if (AMODE == 0) {
            const float* A = (const float*)Aptr;
            for (int i = 0; i < 8; ++i) {
                int id = tid + i * 256;          // 2048 float4 chunks = 128 rows x 16
                int r = id >> 4, c4 = id & 15;
                float4 f = *(const float4*)&A[(size_t)(rowBase + r) * D_DIM + k0 + c4 * 4];
                ushort4 h;
                h.x = f2b(f.x); h.y = f2b(f.y); h.z = f2b(f.z); h.w = f2b(f.w);
                *(ushort4*)&Al[r * 72 + c4 * 4] = h;
            }
        } else {
            const unsigned short* A = (const unsigned short*)Aptr;
            for (int i = 0; i < 4; ++i) {
                int id = tid + i * 256;          // 1024 bf16x8 chunks = 128 rows x 8
                int r = id >> 3, c8 = id & 7;
                *(uint4*)&Al[r * 72 + c8 * 8] =
                    *(const uint4*)&A[(size_t)(rowBase + r) * D_DIM + k0 + c8 * 8];
            }
        }
        for (int i = 0; i < 8; ++i) {
            int id = tid + i * 256;
            int r = id >> 4, c4 = id & 15;
            float4 f = *(const float4*)&W[(size_t)(colBase + r) * D_DIM + k0 + c4 * 4];
            ushort4 h;
            h.x = f2b(f.x); h.y = f2b(f.y); h.z = f2b(f.z); h.w = f2b(f.w);
            *(ushort4*)&Bl[r * 72 + c4 * 4] = h;
        }
        __syncthreads();
        for (int ks = 0; ks < 2; ++ks) {
            bhalf8 af[4], bfr[4];
            for (int mi = 0; mi < 4; ++mi)
                af[mi] = *(const bhalf8*)&Al[(wm + mi * 16 + lr) * 72 + ks * 32 + lq * 8];
            for (int ni = 0; ni < 4; ++ni)
                bfr[ni] = *(const bhalf8*)&Bl[(wn + ni * 16 + lr) * 72 + ks * 32 + lq * 8];
            for (int mi = 0; mi < 4; ++mi)
                for (int ni = 0; ni < 4; ++ni)
                    acc[mi][ni] = __builtin_amdgcn_mfma_f32_16x16x32_bf16(af[mi], bfr[ni],
                                                                          acc[mi][ni], 0, 0, 0);
        }
        __syncthreads();
    }

    // Epilogue. C/D layout (verified m89/m91): col = lane&15, row = (lane>>4)*4 + reg.
    for (int mi = 0; mi < 4; ++mi) {
        for (int ni = 0; ni < 4; ++ni) {
            int col = colBase + wn + ni * 16 + lr;
            float bv = bias[col];
            for (int r = 0; r < 4; ++r) {
                int m = rowBase + wm + mi * 16 + lq * 4 + r;
                float v = acc[mi][ni][r] + bv;
                if (OMODE == 0) {
                    unsigned short* o = (unsigned short*)Out;
                    int b = m >> 10, n = m & 1023, h = col >> 6, dh = col & 63;
                    o[(((size_t)(b * HEADS + h)) << 16) + (n << 6) + dh] = f2b(v);
                } else {
                    float* o = (float*)Out;
                    o[(size_t)m * D_DIM + col] = v;
                }
            }
        }
    }
}

// ---------------------------------------------------------------------------
// Attention: one block = one (b,h) and a 64-row q tile. Two-pass softmax:
// pass 1 gets row max/sum (online) with mask bitmask packed into LDS;
// pass 2 recomputes S, writes weights fp32 to d_out, feeds P (bf16, via LDS
// C->A layout round-trip) into P@V MFMA with LDS-transposed V tile.
// ---------------------------------------------------------------------------
__global__ __launch_bounds__(256) void attn_kernel(const unsigned short* __restrict__ qh,
                                                   const unsigned short* __restrict__ kh,
                                                   const unsigned short* __restrict__ vh,
                                                   const void* __restrict__ mask,
                                                   const int* __restrict__ mflagp,
                                                   float* __restrict__ wout,
                                                   unsigned short* __restrict__ attnb) {
    __shared__ unsigned short ql[64 * 72];
    __shared__ unsigned short kl[64 * 72];
    __shared__ unsigned short vtl[64 * 72];
    __shared__ unsigned short pl[64 * 72];
    __shared__ unsigned int maskw[64][32];  // 64 rows x 1024 bits

    const int tid = threadIdx.x;
    const int lane = tid & 63, wid = tid >> 6;
    const int lr = lane & 15, lq = lane >> 4;
    const int bh = blockIdx.y;          // b*16 + h
    const int row0 = blockIdx.x * 64;
    const size_t hoff = (size_t)bh << 16;  // *SEQ*DHEAD
    const unsigned short* qp = qh + hoff;
    const unsigned short* kp = kh + hoff;
    const unsigned short* vp = vh + hoff;
    const int byteMode = *mflagp;
    const size_t mbase = ((size_t)bh * SEQ + row0) * SEQ;

    // q tile 64x64 bf16 -> LDS, stays resident
    for (int i = 0; i < 2; ++i) {
        int id = tid + i * 256;
        int r = id >> 3, c8 = id & 7;
        *(uint4*)&ql[r * 72 + c8 * 8] = *(const uint4*)&qp[((size_t)(row0 + r) << 6) + c8 * 8];
    }

    float mrow[4], lrow[4];
    for (int r = 0; r < 4; ++r) { mrow[r] = -3e38f; lrow[r] = 0.f; }

    // ---- pass 1: row max + exp-sum ----
    for (int j = 0; j < 16; ++j) {
        __syncthreads();
        for (int i = 0; i < 2; ++i) {
            int id = tid + i * 256;
            int r = id >> 3, c8 = id & 7;
            *(uint4*)&kl[r * 72 + c8 * 8] =
                *(const uint4*)&kp[((size_t)(j * 64 + r) << 6) + c8 * 8];
        }
        // mask -> bitmask (each wave packs its own 16 rows; cols j*64..j*64+63)
        for (int rr = 0; rr < 16; ++rr) {
            int row = wid * 16 + rr;
            size_t mi = mbase + (size_t)row * SEQ + j * 64 + lane;
            int mv = byteMode ? (((const unsigned char*)mask)[mi] != 0)
                              : (((const unsigned int*)mask)[mi] != 0);
            unsigned long long bal = __ballot(mv);
            if (lane == 0) {
                maskw[row][j * 2] = (unsigned int)bal;
                maskw[row][j * 2 + 1] = (unsigned int)(bal >> 32);
            }
        }
        __syncthreads();

        floatx4 sacc[4];
        for (int c = 0; c < 4; ++c)
            for (int r = 0; r < 4; ++r) sacc[c][r] = 0.f;
        for (int ks = 0; ks < 2; ++ks) {
            bhalf8 a = *(const bhalf8*)&ql[(wid * 16 + lr) * 72 + ks * 32 + lq * 8];
            for (int c = 0; c < 4; ++c) {
                bhalf8 bb = *(const bhalf8*)&kl[(c * 16 + lr) * 72 + ks * 32 + lq * 8];
                sacc[c] = __builtin_amdgcn_mfma_f32_16x16x32_bf16(a, bb, sacc[c], 0, 0, 0);
            }
        }
        float mt[4];
        for (int r = 0; r < 4; ++r) mt[r] = -3e38f;
        for (int c = 0; c < 4; ++c) {
            int col = j * 64 + c * 16 + lr;
            for (int r = 0; r < 4; ++r) {
                float s = sacc[c][r] * 0.125f;  // /sqrt(64)
                int row = wid * 16 + lq * 4 + r;
                if ((maskw[row][col >> 5] >> (col & 31)) & 1u) s = -1e10f;
                sacc[c][r] = s;
                mt[r] = fmaxf(mt[r], s);
            }
        }
        for (int o = 1; o < 16; o <<= 1)
            for (int r = 0; r < 4; ++r) mt[r] = fmaxf(mt[r], __shfl_xor(mt[r], o));
        for (int r = 0; r < 4; ++r) {
            float mn = fmaxf(mrow[r], mt[r]);
            float sv = 0.f;
            for (int c = 0; c < 4; ++c) sv += __expf(sacc[c][r] - mn);
            for (int o = 1; o < 16; o <<= 1) sv += __shfl_xor(sv, o);
            lrow[r] = lrow[r] * __expf(mrow[r] - mn) + sv;
            mrow[r] = mn;
        }
    }

    // ---- pass 2: weights out + P@V ----
    float invl[4];
    for (int r = 0; r < 4; ++r) invl[r] = 1.f / lrow[r];
    floatx4 oacc[4];
    for (int c = 0; c < 4; ++c)
        for (int r = 0; r < 4; ++r) oacc[c][r] = 0.f;
    const size_t wrowbase = ((size_t)bh * SEQ + row0) * SEQ;

    for (int j = 0; j < 16; ++j) {
        __syncthreads();
        for (int i = 0; i < 2; ++i) {
            int id = tid + i * 256;
            int r = id >> 3, c8 = id & 7;
            *(uint4*)&kl[r * 72 + c8 * 8] =
                *(const uint4*)&kp[((size_t)(j * 64 + r) << 6) + c8 * 8];
        }
        // V tile transposed into LDS: vtl[dh][n'] so PV B-frags read 16B contiguous
        for (int i = 0; i < 2; ++i) {
            int id = tid + i * 256;
            int n = id & 63, dh0 = (id >> 6) * 8;
            uint4 vv = *(const uint4*)&vp[((size_t)(j * 64 + n) << 6) + dh0];
            const unsigned short* e = (const unsigned short*)&vv;
            for (int t = 0; t < 8; ++t) vtl[(dh0 + t) * 72 + n] = e[t];
        }
        __syncthreads();

        floatx4 sacc[4];
        for (int c = 0; c < 4; ++c)
            for (int r = 0; r < 4; ++r) sacc[c][r] = 0.f;
        for (int ks = 0; ks < 2; ++ks) {
            bhalf8 a = *(const bhalf8*)&ql[(wid * 16 + lr) * 72 + ks * 32 + lq * 8];
            for (int c = 0; c < 4; ++c) {
                bhalf8 bb = *(const bhalf8*)&kl[(c * 16 + lr) * 72 + ks * 32 + lq * 8];
                sacc[c] = __builtin_amdgcn_mfma_f32_16x16x32_bf16(a, bb, sacc[c], 0, 0, 0);
            }
        }
        for (int c = 0; c < 4; ++c) {
            int col = j * 64 + c * 16 + lr;
            for (int r = 0; r < 4; ++r) {
                int row = wid * 16 + lq * 4 + r;
                float s = sacc[c][r] * 0.125f;
                if ((maskw[row][col >> 5] >> (col & 31)) & 1u) s = -1e10f;
                float p = __expf(s - mrow[r]) * invl[r];
                wout[wrowbase + (size_t)row * SEQ + col] = p;
                pl[row * 72 + c * 16 + lr] = f2b(p);  // same wave writes & reads its strip
            }
        }
        // P@V: A-frag from pl (own wave's 16-row strip), B-frag from vtl
        for (int ks = 0; ks < 2; ++ks) {
            bhalf8 a = *(const bhalf8*)&pl[(wid * 16 + lr) * 72 + ks * 32 + lq * 8];
            for (int c = 0; c < 4; ++c) {
                bhalf8 bb = *(const bhalf8*)&vtl[(c * 16 + lr) * 72 + ks * 32 + lq * 8];
                oacc[c] = __builtin_amdgcn_mfma_f32_16x16x32_bf16(a, bb, oacc[c], 0, 0, 0);
            }
        }
    }

    // O -> attnb in merged [b, n, h*64+dh] bf16 layout for the output projection
    const int b = bh >> 4, h = bh & 15;
    for (int c = 0; c < 4; ++c) {
        int colg = h * 64 + c * 16 + lr;
        for (int r = 0; r < 4; ++r) {
            int n = row0 + wid * 16 + lq * 4 + r;
            attnb[(size_t)(b * SEQ + n) * D_DIM + colg] = f2b(oacc[c][r]);
        }
    }
}

// ---------------------------------------------------------------------------
extern "C" void kernel_launch(void* const* d_in, const int* in_sizes, int n_in,
                              void* d_out, int out_size, void* d_ws, size_t ws_size,
                              hipStream_t stream) {
    const float* Q = (const float*)d_in[0];
    const float* K = (const float*)d_in[1];
    const float* V = (const float*)d_in[2];
    const void* mask = d_in[3];
    const float* Wq = (const float*)d_in[4];
    const float* bq = (const float*)d_in[5];
    const float* Wk = (const float*)d_in[6];
    const float* bk = (const float*)d_in[7];
    const float* Wv = (const float*)d_in[8];
    const float* bv = (const float*)d_in[9];
    const float* Wo = (const float*)d_in[10];
    const float* bo = (const float*)d_in[11];

    char* ws = (char*)d_ws;
    int* mflag = (int*)ws;
    unsigned short* qhb = (unsigned short*)(ws + 256);     // [4,16,1024,64] bf16
    unsigned short* khb = qhb + 4194304;
    unsigned short* vhb = khb + 4194304;
    unsigned short* attnb = vhb + 4194304;                 // [4096,1024] bf16
    // total ws use: 256 + 4*8MB = ~33.6MB

    float* xout = (float*)d_out;                           // [4096,1024] fp32
    float* wout = xout + (size_t)BATCH * SEQ * D_DIM;      // [4,16,1024,1024] fp32

    dim3 blk(256);
    detect_mask_kernel<<<1, blk, 0, stream>>>((const unsigned int*)mask, mflag);

    dim3 g(8, 32);  // N/128, M/128
    gemm_bt<0, 0><<<g, blk, 0, stream>>>(Q, Wq, bq, qhb);
    gemm_bt<0, 0><<<g, blk, 0, stream>>>(K, Wk, bk, khb);
    gemm_bt<0, 0><<<g, blk, 0, stream>>>(V, Wv, bv, vhb);

    attn_kernel<<<dim3(16, 64), blk, 0, stream>>>(qhb, khb, vhb, mask, mflag, wout, attnb);

    gemm_bt<1, 1><<<g, blk, 0, stream>>>(attnb, Wo, bo, xout);
}

// Round 2
// 969.348 us; speedup vs baseline: 1.4761x; 1.4761x over previous
//
#include <hip/hip_runtime.h>

// MHA fused forward: x = (softmax(split(QWq^T+bq) @ split(KWk^T+bk)^T / 8, mask) @ split(VWv^T+bv)) merged @ Wo^T + bo
// B=4 N=1024 D=1024 H=16 DH=64.  Outputs: x [4,1024,1024] fp32 then weights [4,16,1024,1024] fp32.

#define SEQ   1024
#define D_DIM 1024
#define HEADS 16
#define DHEAD 64
#define BATCH 4

typedef __attribute__((ext_vector_type(8))) short bhalf8;
typedef __attribute__((ext_vector_type(4))) float floatx4;

static __device__ __forceinline__ unsigned short f2b(float f) {
    // fp32 -> bf16 round-to-nearest-even (inputs are finite randoms; NaN path not needed)
    unsigned int u = __float_as_uint(f);
    u += 0x7FFFu + ((u >> 16) & 1u);
    return (unsigned short)(u >> 16);
}

// ---------------------------------------------------------------------------
// Mask dtype probe. bool mask may arrive as uint8, int32 or fp32. Byte mode
// (10% ones): P(a word is not in {0,1,0x3F800000}) ~= 0.27, so 16K words give
// miss prob 0.73^16384 ~ 0. Read 64KB as uint4 (16 independent loads/thread,
// all in flight -> ~1 HBM latency), reduce in LDS, single block writes flag.
// ---------------------------------------------------------------------------
__global__ __launch_bounds__(256) void detect_mask_kernel(const uint4* __restrict__ m,
                                                          int* __restrict__ flag) {
    __shared__ int found;
    if (threadIdx.x == 0) found = 0;
    __syncthreads();
    unsigned int bad = 0;
#pragma unroll
    for (int i = 0; i < 16; ++i) {
        uint4 w = m[threadIdx.x + i * 256];  // 4096 uint4 = 64KB
        unsigned int a = w.x, b = w.y, c = w.z, d = w.w;
        bad |= (a != 0u && a != 1u && a != 0x3F800000u);
        bad |= (b != 0u && b != 1u && b != 0x3F800000u);
        bad |= (c != 0u && c != 1u && c != 0x3F800000u);
        bad |= (d != 0u && d != 1u && d != 0x3F800000u);
    }
    if (bad) atomicOr(&found, 1);
    __syncthreads();
    if (threadIdx.x == 0) *flag = found;  // 1 = byte elements, 0 = 4-byte elements
}

// ---------------------------------------------------------------------------
// GEMM: Out[m, n] = sum_k A[m, k] * W[n, k] + bias[n]   (torch Linear, W row-major [out,in])
// M=4096, N=1024, K=1024. 128x128 tile, BK=64, 4 waves (2x2), 4x4 MFMA tiles/wave.
// AMODE 0: A fp32 (convert to bf16 during staging); AMODE 1: A bf16.
// OMODE 0: write bf16 scattered to [b,h,n,dh] (+bias); OMODE 1: write fp32 row-major (+bias).
// ---------------------------------------------------------------------------
template <int AMODE, int OMODE>
__global__ __launch_bounds__(256) void gemm_bt(const void* __restrict__ Aptr,
                                               const float* __restrict__ W,
                                               const float* __restrict__ bias,
                                               void* __restrict__ Out) {
    __shared__ unsigned short Al[128 * 72];  // +8 pad: row stride 144B -> 2-way bank alias (free)
    __shared__ unsigned short Bl[128 * 72];

    const int tid = threadIdx.x;
    const int lane = tid & 63, wid = tid >> 6;
    const int lr = lane & 15, lq = lane >> 4;
    const int wm = (wid & 1) * 64, wn = (wid >> 1) * 64;
    const int rowBase = blockIdx.y * 128;
    const int colBase = blockIdx.x * 128;

    floatx4 acc[4][4];
    for (int mi = 0; mi < 4; ++mi)
        for (int ni = 0; ni < 4; ++ni)
            for (int r = 0; r < 4; ++r) acc[mi][ni][r] = 0.f;

    for (int k0 = 0; k0 < D_DIM; k0 += 64) {
        if (AMODE == 0) {
            const float* A = (const float*)Aptr;
            for (int i = 0; i < 8; ++i) {
                int id = tid + i * 256;          // 2048 float4 chunks = 128 rows x 16
                int r = id >> 4, c4 = id & 15;
                float4 f = *(const float4*)&A[(size_t)(rowBase + r) * D_DIM + k0 + c4 * 4];
                ushort4 h;
                h.x = f2b(f.x); h.y = f2b(f.y); h.z = f2b(f.z); h.w = f2b(f.w);
                *(ushort4*)&Al[r * 72 + c4 * 4] = h;
            }
        } else {
            const unsigned short* A = (const unsigned short*)Aptr;
            for (int i = 0; i < 4; ++i) {
                int id = tid + i * 256;          // 1024 bf16x8 chunks = 128 rows x 8
                int r = id >> 3, c8 = id & 7;
                *(uint4*)&Al[r * 72 + c8 * 8] =
                    *(const uint4*)&A[(size_t)(rowBase + r) * D_DIM + k0 + c8 * 8];
            }
        }
        for (int i = 0; i < 8; ++i) {
            int id = tid + i * 256;
            int r = id >> 4, c4 = id & 15;
            float4 f = *(const float4*)&W[(size_t)(colBase + r) * D_DIM + k0 + c4 * 4];
            ushort4 h;
            h.x = f2b(f.x); h.y = f2b(f.y); h.z = f2b(f.z); h.w = f2b(f.w);
            *(ushort4*)&Bl[r * 72 + c4 * 4] = h;
        }
        __syncthreads();
        for (int ks = 0; ks < 2; ++ks) {
            bhalf8 af[4], bfr[4];
            for (int mi = 0; mi < 4; ++mi)
                af[mi] = *(const bhalf8*)&Al[(wm + mi * 16 + lr) * 72 + ks * 32 + lq * 8];
            for (int ni = 0; ni < 4; ++ni)
                bfr[ni] = *(const bhalf8*)&Bl[(wn + ni * 16 + lr) * 72 + ks * 32 + lq * 8];
            for (int mi = 0; mi < 4; ++mi)
                for (int ni = 0; ni < 4; ++ni)
                    acc[mi][ni] = __builtin_amdgcn_mfma_f32_16x16x32_bf16(af[mi], bfr[ni],
                                                                          acc[mi][ni], 0, 0, 0);
        }
        __syncthreads();
    }

    // Epilogue. C/D layout (verified m89/m91): col = lane&15, row = (lane>>4)*4 + reg.
    for (int mi = 0; mi < 4; ++mi) {
        for (int ni = 0; ni < 4; ++ni) {
            int col = colBase + wn + ni * 16 + lr;
            float bv = bias[col];
            for (int r = 0; r < 4; ++r) {
                int m = rowBase + wm + mi * 16 + lq * 4 + r;
                float v = acc[mi][ni][r] + bv;
                if (OMODE == 0) {
                    unsigned short* o = (unsigned short*)Out;
                    int b = m >> 10, n = m & 1023, h = col >> 6, dh = col & 63;
                    o[(((size_t)(b * HEADS + h)) << 16) + (n << 6) + dh] = f2b(v);
                } else {
                    float* o = (float*)Out;
                    o[(size_t)m * D_DIM + col] = v;
                }
            }
        }
    }
}

// ---------------------------------------------------------------------------
// Attention: one block = one (b,h) and a 64-row q tile. Two-pass softmax:
// pass 1 gets row max/sum (online) with mask bitmask packed into LDS;
// pass 2 recomputes S, writes weights fp32 to d_out, feeds P (bf16, via LDS
// C->A layout round-trip) into P@V MFMA with LDS-transposed V tile.
// ---------------------------------------------------------------------------
__global__ __launch_bounds__(256) void attn_kernel(const unsigned short* __restrict__ qh,
                                                   const unsigned short* __restrict__ kh,
                                                   const unsigned short* __restrict__ vh,
                                                   const void* __restrict__ mask,
                                                   const int* __restrict__ mflagp,
                                                   float* __restrict__ wout,
                                                   unsigned short* __restrict__ attnb) {
    __shared__ unsigned short ql[64 * 72];
    __shared__ unsigned short kl[64 * 72];
    __shared__ unsigned short vtl[64 * 72];
    __shared__ unsigned short pl[64 * 72];
    __shared__ unsigned int maskw[64][32];  // 64 rows x 1024 bits

    const int tid = threadIdx.x;
    const int lane = tid & 63, wid = tid >> 6;
    const int lr = lane & 15, lq = lane >> 4;
    const int bh = blockIdx.y;          // b*16 + h
    const int row0 = blockIdx.x * 64;
    const size_t hoff = (size_t)bh << 16;  // *SEQ*DHEAD
    const unsigned short* qp = qh + hoff;
    const unsigned short* kp = kh + hoff;
    const unsigned short* vp = vh + hoff;
    const int byteMode = *mflagp;
    const size_t mbase = ((size_t)bh * SEQ + row0) * SEQ;

    // q tile 64x64 bf16 -> LDS, stays resident
    for (int i = 0; i < 2; ++i) {
        int id = tid + i * 256;
        int r = id >> 3, c8 = id & 7;
        *(uint4*)&ql[r * 72 + c8 * 8] = *(const uint4*)&qp[((size_t)(row0 + r) << 6) + c8 * 8];
    }

    float mrow[4], lrow[4];
    for (int r = 0; r < 4; ++r) { mrow[r] = -3e38f; lrow[r] = 0.f; }

    // ---- pass 1: row max + exp-sum ----
    for (int j = 0; j < 16; ++j) {
        __syncthreads();
        for (int i = 0; i < 2; ++i) {
            int id = tid + i * 256;
            int r = id >> 3, c8 = id & 7;
            *(uint4*)&kl[r * 72 + c8 * 8] =
                *(const uint4*)&kp[((size_t)(j * 64 + r) << 6) + c8 * 8];
        }
        // mask -> bitmask (each wave packs its own 16 rows; cols j*64..j*64+63)
        for (int rr = 0; rr < 16; ++rr) {
            int row = wid * 16 + rr;
            size_t mi = mbase + (size_t)row * SEQ + j * 64 + lane;
            int mv = byteMode ? (((const unsigned char*)mask)[mi] != 0)
                              : (((const unsigned int*)mask)[mi] != 0);
            unsigned long long bal = __ballot(mv);
            if (lane == 0) {
                maskw[row][j * 2] = (unsigned int)bal;
                maskw[row][j * 2 + 1] = (unsigned int)(bal >> 32);
            }
        }
        __syncthreads();

        floatx4 sacc[4];
        for (int c = 0; c < 4; ++c)
            for (int r = 0; r < 4; ++r) sacc[c][r] = 0.f;
        for (int ks = 0; ks < 2; ++ks) {
            bhalf8 a = *(const bhalf8*)&ql[(wid * 16 + lr) * 72 + ks * 32 + lq * 8];
            for (int c = 0; c < 4; ++c) {
                bhalf8 bb = *(const bhalf8*)&kl[(c * 16 + lr) * 72 + ks * 32 + lq * 8];
                sacc[c] = __builtin_amdgcn_mfma_f32_16x16x32_bf16(a, bb, sacc[c], 0, 0, 0);
            }
        }
        float mt[4];
        for (int r = 0; r < 4; ++r) mt[r] = -3e38f;
        for (int c = 0; c < 4; ++c) {
            int col = j * 64 + c * 16 + lr;
            for (int r = 0; r < 4; ++r) {
                float s = sacc[c][r] * 0.125f;  // /sqrt(64)
                int row = wid * 16 + lq * 4 + r;
                if ((maskw[row][col >> 5] >> (col & 31)) & 1u) s = -1e10f;
                sacc[c][r] = s;
                mt[r] = fmaxf(mt[r], s);
            }
        }
        for (int o = 1; o < 16; o <<= 1)
            for (int r = 0; r < 4; ++r) mt[r] = fmaxf(mt[r], __shfl_xor(mt[r], o));
        for (int r = 0; r < 4; ++r) {
            float mn = fmaxf(mrow[r], mt[r]);
            float sv = 0.f;
            for (int c = 0; c < 4; ++c) sv += __expf(sacc[c][r] - mn);
            for (int o = 1; o < 16; o <<= 1) sv += __shfl_xor(sv, o);
            lrow[r] = lrow[r] * __expf(mrow[r] - mn) + sv;
            mrow[r] = mn;
        }
    }

    // ---- pass 2: weights out + P@V ----
    float invl[4];
    for (int r = 0; r < 4; ++r) invl[r] = 1.f / lrow[r];
    floatx4 oacc[4];
    for (int c = 0; c < 4; ++c)
        for (int r = 0; r < 4; ++r) oacc[c][r] = 0.f;
    const size_t wrowbase = ((size_t)bh * SEQ + row0) * SEQ;

    for (int j = 0; j < 16; ++j) {
        __syncthreads();
        for (int i = 0; i < 2; ++i) {
            int id = tid + i * 256;
            int r = id >> 3, c8 = id & 7;
            *(uint4*)&kl[r * 72 + c8 * 8] =
                *(const uint4*)&kp[((size_t)(j * 64 + r) << 6) + c8 * 8];
        }
        // V tile transposed into LDS: vtl[dh][n'] so PV B-frags read 16B contiguous
        for (int i = 0; i < 2; ++i) {
            int id = tid + i * 256;
            int n = id & 63, dh0 = (id >> 6) * 8;
            uint4 vv = *(const uint4*)&vp[((size_t)(j * 64 + n) << 6) + dh0];
            const unsigned short* e = (const unsigned short*)&vv;
            for (int t = 0; t < 8; ++t) vtl[(dh0 + t) * 72 + n] = e[t];
        }
        __syncthreads();

        floatx4 sacc[4];
        for (int c = 0; c < 4; ++c)
            for (int r = 0; r < 4; ++r) sacc[c][r] = 0.f;
        for (int ks = 0; ks < 2; ++ks) {
            bhalf8 a = *(const bhalf8*)&ql[(wid * 16 + lr) * 72 + ks * 32 + lq * 8];
            for (int c = 0; c < 4; ++c) {
                bhalf8 bb = *(const bhalf8*)&kl[(c * 16 + lr) * 72 + ks * 32 + lq * 8];
                sacc[c] = __builtin_amdgcn_mfma_f32_16x16x32_bf16(a, bb, sacc[c], 0, 0, 0);
            }
        }
        for (int c = 0; c < 4; ++c) {
            int col = j * 64 + c * 16 + lr;
            for (int r = 0; r < 4; ++r) {
                int row = wid * 16 + lq * 4 + r;
                float s = sacc[c][r] * 0.125f;
                if ((maskw[row][col >> 5] >> (col & 31)) & 1u) s = -1e10f;
                float p = __expf(s - mrow[r]) * invl[r];
                wout[wrowbase + (size_t)row * SEQ + col] = p;
                pl[row * 72 + c * 16 + lr] = f2b(p);  // same wave writes & reads its strip
            }
        }
        // P@V: A-frag from pl (own wave's 16-row strip), B-frag from vtl
        for (int ks = 0; ks < 2; ++ks) {
            bhalf8 a = *(const bhalf8*)&pl[(wid * 16 + lr) * 72 + ks * 32 + lq * 8];
            for (int c = 0; c < 4; ++c) {
                bhalf8 bb = *(const bhalf8*)&vtl[(c * 16 + lr) * 72 + ks * 32 + lq * 8];
                oacc[c] = __builtin_amdgcn_mfma_f32_16x16x32_bf16(a, bb, oacc[c], 0, 0, 0);
            }
        }
    }

    // O -> attnb in merged [b, n, h*64+dh] bf16 layout for the output projection
    const int b = bh >> 4, h = bh & 15;
    for (int c = 0; c < 4; ++c) {
        int colg = h * 64 + c * 16 + lr;
        for (int r = 0; r < 4; ++r) {
            int n = row0 + wid * 16 + lq * 4 + r;
            attnb[(size_t)(b * SEQ + n) * D_DIM + colg] = f2b(oacc[c][r]);
        }
    }
}

// ---------------------------------------------------------------------------
extern "C" void kernel_launch(void* const* d_in, const int* in_sizes, int n_in,
                              void* d_out, int out_size, void* d_ws, size_t ws_size,
                              hipStream_t stream) {
    const float* Q = (const float*)d_in[0];
    const float* K = (const float*)d_in[1];
    const float* V = (const float*)d_in[2];
    const void* mask = d_in[3];
    const float* Wq = (const float*)d_in[4];
    const float* bq = (const float*)d_in[5];
    const float* Wk = (const float*)d_in[6];
    const float* bk = (const float*)d_in[7];
    const float* Wv = (const float*)d_in[8];
    const float* bv = (const float*)d_in[9];
    const float* Wo = (const float*)d_in[10];
    const float* bo = (const float*)d_in[11];

    char* ws = (char*)d_ws;
    int* mflag = (int*)ws;
    unsigned short* qhb = (unsigned short*)(ws + 256);     // [4,16,1024,64] bf16
    unsigned short* khb = qhb + 4194304;
    unsigned short* vhb = khb + 4194304;
    unsigned short* attnb = vhb + 4194304;                 // [4096,1024] bf16
    // total ws use: 256 + 4*8MB = ~33.6MB

    float* xout = (float*)d_out;                           // [4096,1024] fp32
    float* wout = xout + (size_t)BATCH * SEQ * D_DIM;      // [4,16,1024,1024] fp32

    dim3 blk(256);
    detect_mask_kernel<<<1, blk, 0, stream>>>((const uint4*)mask, mflag);

    dim3 g(8, 32);  // N/128, M/128
    gemm_bt<0, 0><<<g, blk, 0, stream>>>(Q, Wq, bq, qhb);
    gemm_bt<0, 0><<<g, blk, 0, stream>>>(K, Wk, bk, khb);
    gemm_bt<0, 0><<<g, blk, 0, stream>>>(V, Wv, bv, vhb);

    attn_kernel<<<dim3(16, 64), blk, 0, stream>>>(qhb, khb, vhb, mask, mflag, wout, attnb);

    gemm_bt<1, 1><<<g, blk, 0, stream>>>(attnb, Wo, bo, xout);
}